// Round 15
// baseline (604.294 us; speedup 1.0000x reference)
//
#include <hip/hip_runtime.h>
#include <math.h>

// Problem constants
#define Nn 50000
#define Ee 800000
#define Bb 256
#define Hh 64
#define TPB 256
#define CHUNK 512

__device__ __forceinline__ float tanh_fast(float x) {
    // tanh(x) = 1 - 2/(exp(2x)+1); exp overflow -> 1, underflow -> -1 (correct limits)
    return 1.f - 2.f / (__expf(2.f * x) + 1.f);
}

// ---------------- embed: h = x @ W(4x64) + b ----------------
__global__ void k_embed(const float* __restrict__ x, const float* __restrict__ W,
                        const float* __restrict__ b, float* __restrict__ h) {
    int idx = blockIdx.x * blockDim.x + threadIdx.x;
    if (idx >= Nn * Hh) return;
    int n = idx >> 6, j = idx & 63;
    float acc = b[j];
#pragma unroll
    for (int d = 0; d < 4; ++d) acc += x[n * 4 + d] * W[d * Hh + j];
    h[idx] = acc;
}

// ---------------- CSR build ----------------
__global__ void k_hist(const int* __restrict__ dst, int* __restrict__ counts) {
    int e = blockIdx.x * blockDim.x + threadIdx.x;
    if (e < Ee) atomicAdd(&counts[dst[e]], 1);
}

__global__ void k_scan1(const int* __restrict__ counts, int* __restrict__ off,
                        int* __restrict__ chunksum) {
    __shared__ int s[CHUNK];
    int t = threadIdx.x;
    int base = blockIdx.x * CHUNK;
    int v = (base + t < Nn) ? counts[base + t] : 0;
    s[t] = v;
    __syncthreads();
    for (int d = 1; d < CHUNK; d <<= 1) {
        int u = (t >= d) ? s[t - d] : 0;
        __syncthreads();
        s[t] += u;
        __syncthreads();
    }
    if (base + t < Nn) off[base + t + 1] = s[t];
    if (t == CHUNK - 1) chunksum[blockIdx.x] = s[t];
}

__global__ void k_scan2(int* __restrict__ chunksum, int nch) {
    if (blockIdx.x == 0 && threadIdx.x == 0) {
        int run = 0;
        for (int i = 0; i < nch; ++i) { int v = chunksum[i]; chunksum[i] = run; run += v; }
    }
}

// scan3 + cursor init fused
__global__ void k_scan3(int* __restrict__ off, const int* __restrict__ chunkoff,
                        int* __restrict__ cursor) {
    int i = blockIdx.x * blockDim.x + threadIdx.x;
    if (i > Nn) return;
    int v;
    if (i == 0) { off[0] = 0; v = 0; }
    else {
        v = off[i] + chunkoff[(i - 1) >> 9];  // CHUNK=512
        off[i] = v;
    }
    if (i < Nn) cursor[i] = v;
}

// scatter: single 8B packed random write per edge
__global__ void k_scatter(const int* __restrict__ src, const int* __restrict__ dst,
                          const float* __restrict__ ea, int* __restrict__ cursor,
                          int2* __restrict__ epack) {
    int e = blockIdx.x * blockDim.x + threadIdx.x;
    if (e >= Ee) return;
    int d = dst[e];
    int p = atomicAdd(&cursor[d], 1);
    epack[p] = make_int2(src[e], __float_as_int(ea[e]));
}

// ---------------- conv linear: lane = output col (coalesced weights), 4 nodes/thread ----
__global__ __launch_bounds__(256) void k_lin(const float* __restrict__ h,
                      const float* __restrict__ Wl, const float* __restrict__ bl,
                      const float* __restrict__ Wr, const float* __restrict__ br,
                      float* __restrict__ xl, float* __restrict__ xr) {
    int lane = threadIdx.x & 63, w = threadIdx.x >> 6;
    int n0 = blockIdx.x * 16 + w * 4;      // 4 nodes per wave, 16 per block
    float al[4], ar[4];
#pragma unroll
    for (int q = 0; q < 4; ++q) { al[q] = bl[lane]; ar[q] = br[lane]; }
    for (int i4 = 0; i4 < 16; ++i4) {
        float4 hv[4];
#pragma unroll
        for (int q = 0; q < 4; ++q)
            hv[q] = *(const float4*)(h + (n0 + q) * 64 + i4 * 4);   // wave-uniform broadcast
#pragma unroll
        for (int u = 0; u < 4; ++u) {
            int i = i4 * 4 + u;
            float wlv = Wl[i * 64 + lane];   // coalesced across lanes
            float wrv = Wr[i * 64 + lane];
#pragma unroll
            for (int q = 0; q < 4; ++q) {
                float hq = ((const float*)&hv[q])[u];
                al[q] += hq * wlv;
                ar[q] += hq * wrv;
            }
        }
    }
#pragma unroll
    for (int q = 0; q < 4; ++q) {
        xl[(n0 + q) * 64 + lane] = al[q];
        xr[(n0 + q) * 64 + lane] = ar[q];
    }
}

// ---------------- fused GATv2 conv, 16-lane-group float4 layout ----------------
__global__ void k_conv(const float* __restrict__ xl, const float* __restrict__ xr,
                       const int2* __restrict__ epack, const int* __restrict__ off,
                       const float* __restrict__ We, const float* __restrict__ att,
                       const float* __restrict__ bias, float* __restrict__ hout) {
    int gid = blockIdx.x * blockDim.x + threadIdx.x;
    int n = gid >> 6, lane = gid & 63;
    if (n >= Nn) return;
    int g = lane >> 4, l16 = lane & 15;
    int s = off[n], t = off[n + 1];
    float4 xr4 = *(const float4*)(xr + (size_t)n * 64 + l16 * 4);
    float4 We4 = *(const float4*)(We + l16 * 4);
    float4 at4 = *(const float4*)(att + l16 * 4);
    float4 acc = make_float4(0.f, 0.f, 0.f, 0.f);
    float m_run = -1e30f, s_run = 0.f;
    for (int c = s; c < t; c += 4) {
        int e = c + g;
        bool valid = e < t;
        int2 pk = valid ? epack[e] : epack[c];
        int sr = pk.x;
        float ceav = valid ? __int_as_float(pk.y) : 0.f;
        float4 row = *(const float4*)(xl + (size_t)sr * 64 + l16 * 4);
        float mx_ = row.x + xr4.x + ceav * We4.x;
        float my_ = row.y + xr4.y + ceav * We4.y;
        float mz_ = row.z + xr4.z + ceav * We4.z;
        float mw_ = row.w + xr4.w + ceav * We4.w;
        mx_ = mx_ > 0.f ? mx_ : 0.2f * mx_;
        my_ = my_ > 0.f ? my_ : 0.2f * my_;
        mz_ = mz_ > 0.f ? mz_ : 0.2f * mz_;
        mw_ = mw_ > 0.f ? mw_ : 0.2f * mw_;
        float pv = mx_ * at4.x + my_ * at4.y + mz_ * at4.z + mw_ * at4.w;
#pragma unroll
        for (int o = 1; o < 16; o <<= 1) pv += __shfl_xor(pv, o);
        float ee = valid ? pv : -1e30f;
        float cm = ee;
        cm = fmaxf(cm, __shfl_xor(cm, 16));
        cm = fmaxf(cm, __shfl_xor(cm, 32));
        float m_new = fmaxf(m_run, cm);
        float f = __expf(m_run - m_new);
        acc.x *= f; acc.y *= f; acc.z *= f; acc.w *= f; s_run *= f;
        float w = __expf(ee - m_new);
        acc.x += w * row.x; acc.y += w * row.y;
        acc.z += w * row.z; acc.w += w * row.w;
        s_run += w;
        m_run = m_new;
    }
#pragma unroll
    for (int o = 16; o <= 32; o <<= 1) {
        acc.x += __shfl_xor(acc.x, o); acc.y += __shfl_xor(acc.y, o);
        acc.z += __shfl_xor(acc.z, o); acc.w += __shfl_xor(acc.w, o);
        s_run += __shfl_xor(s_run, o);
    }
    float4 b4 = *(const float4*)(bias + l16 * 4);
    float inv = (t > s) ? 1.f / s_run : 0.f;
    float4 o4;
    o4.x = acc.x * inv + b4.x; o4.y = acc.y * inv + b4.y;
    o4.z = acc.z * inv + b4.z; o4.w = acc.w * inv + b4.w;
    o4.x = o4.x / (1.f + __expf(-o4.x));
    o4.y = o4.y / (1.f + __expf(-o4.y));
    o4.z = o4.z / (1.f + __expf(-o4.z));
    o4.w = o4.w / (1.f + __expf(-o4.w));
    if (lane < 16) *(float4*)(hout + (size_t)n * 64 + l16 * 4) = o4;
}

// ---------------- fused RK4, 256 threads / 16 nodes (halved per-thread work) ----
// phase1: k=t&127, kg=t>>7 (2 groups x 8 nodes/thread): z=tanh(y@W1+b1)
// phase2: j=t&63, wg=t>>6 (4 groups x 4 nodes/thread): kst=z@W2+b2, ksum+=w*kst,
//         y_next = h0 + cf*kst. h0/ksum in registers (phase-2 layout).
__global__ __launch_bounds__(256) void k_ode4(float* __restrict__ h,
        const float* __restrict__ W1, const float* __restrict__ b1,
        const float* __restrict__ W2, const float* __restrict__ b2) {
    __shared__ float yt[16][64];
    __shared__ float zt[16][128];
    int t = threadIdx.x;
    int nb = blockIdx.x * 16;
    int j = t & 63, wg = t >> 6;
    int k = t & 127, kg = t >> 7;
    // stage y0 = h into LDS (cooperative, coalesced): 256 float4
    {
        int nn = t >> 4, jj = (t & 15) * 4;
        *(float4*)&yt[nn][jj] = *(const float4*)(h + (size_t)(nb + nn) * 64 + jj);
    }
    // h0 + ksum registers (phase-2 layout: 4 nodes per thread)
    float h0[4], ksum[4];
#pragma unroll
    for (int q = 0; q < 4; ++q) {
        h0[q] = h[(size_t)(nb + wg * 4 + q) * 64 + j];
        ksum[q] = 0.f;
    }
    __syncthreads();
#pragma unroll
    for (int s = 0; s < 4; ++s) {
        const float wgt = (s == 1 || s == 2) ? 2.f : 1.f;
        const float cf = (s == 2) ? 1.f : 0.5f;
        {   // phase 1: 8 nodes per thread
            float acc1[8];
#pragma unroll
            for (int q = 0; q < 8; ++q) acc1[q] = b1[k];
            for (int i4 = 0; i4 < 16; ++i4) {
                float wv4[4];
#pragma unroll
                for (int u = 0; u < 4; ++u) wv4[u] = W1[(i4 * 4 + u) * 128 + k];
                float4 yv[8];
#pragma unroll
                for (int q8 = 0; q8 < 8; ++q8)
                    yv[q8] = *(const float4*)&yt[kg * 8 + q8][i4 * 4];
#pragma unroll
                for (int u = 0; u < 4; ++u)
#pragma unroll
                    for (int q8 = 0; q8 < 8; ++q8)
                        acc1[q8] += ((const float*)&yv[q8])[u] * wv4[u];
            }
#pragma unroll
            for (int q = 0; q < 8; ++q) zt[kg * 8 + q][k] = tanh_fast(acc1[q]);
        }
        __syncthreads();
        {   // phase 2: 4 nodes per thread
            float acc2[4];
#pragma unroll
            for (int q = 0; q < 4; ++q) acc2[q] = b2[j];
            for (int k4 = 0; k4 < 32; ++k4) {
                float wv2[4];
#pragma unroll
                for (int u = 0; u < 4; ++u) wv2[u] = W2[(k4 * 4 + u) * 64 + j];
                float4 zv[4];
#pragma unroll
                for (int q = 0; q < 4; ++q)
                    zv[q] = *(const float4*)&zt[wg * 4 + q][k4 * 4];
#pragma unroll
                for (int u = 0; u < 4; ++u)
#pragma unroll
                    for (int q = 0; q < 4; ++q)
                        acc2[q] += ((const float*)&zv[q])[u] * wv2[u];
            }
#pragma unroll
            for (int q = 0; q < 4; ++q) {
                ksum[q] += wgt * acc2[q];
                if (s < 3) yt[wg * 4 + q][j] = h0[q] + cf * acc2[q];
            }
        }
        __syncthreads();
    }
    // epilogue: h = h0 + ksum/6
#pragma unroll
    for (int q = 0; q < 4; ++q)
        h[(size_t)(nb + wg * 4 + q) * 64 + j] = h0[q] + ksum[q] * (1.f / 6.f);
}

// ---------------- pooling ----------------
__global__ void k_binit(int* __restrict__ gs, int* __restrict__ ge) {
    int b = threadIdx.x;
    if (b < Bb) { gs[b] = 0; ge[b] = 0; }
}

__global__ void k_bounds(const int* __restrict__ batch, int* __restrict__ gs,
                         int* __restrict__ ge) {
    int n = blockIdx.x * blockDim.x + threadIdx.x;
    if (n >= Nn) return;
    int b = batch[n];
    if (n == 0 || batch[n - 1] != b) gs[b] = n;
    if (n == Nn - 1 || batch[n + 1] != b) ge[b] = n + 1;
}

__global__ void k_pool(const float* __restrict__ h, const int* __restrict__ gs,
                       const int* __restrict__ ge, float* __restrict__ g) {
    int b = blockIdx.x;
    int s = gs[b], e = ge[b];
    int w = threadIdx.x >> 6, lane = threadIdx.x & 63;
    float sum = 0.f, mx = -1e30f;
    for (int n = s + w; n < e; n += 4) {
        float v = h[n * Hh + lane];
        sum += v;
        mx = fmaxf(mx, v);
    }
    __shared__ float ssum[4][64], smx[4][64];
    ssum[w][lane] = sum;
    smx[w][lane] = mx;
    __syncthreads();
    if (threadIdx.x < 64) {
        int j = threadIdx.x;
        float su = ssum[0][j] + ssum[1][j] + ssum[2][j] + ssum[3][j];
        float m2 = fmaxf(fmaxf(smx[0][j], smx[1][j]), fmaxf(smx[2][j], smx[3][j]));
        int cnt = e - s;
        g[b * 2 * Hh + j] = (cnt > 0) ? su / (float)cnt : 0.f;
        g[b * 2 * Hh + Hh + j] = (cnt > 0) ? m2 : 0.f;
    }
}

// ---------------- predictor head: wave per graph ----------------
__global__ void k_pred(const float* __restrict__ g, const float* __restrict__ W1,
                       const float* __restrict__ b1, const float* __restrict__ W2,
                       const float* __restrict__ b2, float* __restrict__ out) {
    int gid = blockIdx.x * blockDim.x + threadIdx.x;
    int b = gid >> 6, lane = gid & 63;
    if (b >= Bb) return;
    int hh = lane & 31, half = lane >> 5;
    const float* gr = g + b * 2 * Hh + half * Hh;
    float a = 0.f;
#pragma unroll 8
    for (int i = 0; i < Hh; ++i) a += gr[i] * W1[(half * Hh + i) * 32 + hh];
    a += __shfl_xor(a, 32);
    a += b1[hh];
    float sl = a / (1.f + expf(-a));
    float partial = (half == 0) ? sl * W2[hh] : 0.f;
#pragma unroll
    for (int o = 32; o > 0; o >>= 1) partial += __shfl_xor(partial, o);
    if (lane == 0) out[b] = partial + b2[0];
}

extern "C" void kernel_launch(void* const* d_in, const int* in_sizes, int n_in,
                              void* d_out, int out_size, void* d_ws, size_t ws_size,
                              hipStream_t stream) {
    const float* x     = (const float*)d_in[0];
    const int*   ei    = (const int*)d_in[1];
    const float* ea    = (const float*)d_in[2];
    const int*   batch = (const int*)d_in[3];
    const float* embW  = (const float*)d_in[4];
    const float* embB  = (const float*)d_in[5];
    const float* c1Wl = (const float*)d_in[6];  const float* c1bl = (const float*)d_in[7];
    const float* c1Wr = (const float*)d_in[8];  const float* c1br = (const float*)d_in[9];
    const float* c1We = (const float*)d_in[10]; const float* c1att = (const float*)d_in[11];
    const float* c1bias = (const float*)d_in[12];
    const float* c2Wl = (const float*)d_in[13]; const float* c2bl = (const float*)d_in[14];
    const float* c2Wr = (const float*)d_in[15]; const float* c2br = (const float*)d_in[16];
    const float* c2We = (const float*)d_in[17]; const float* c2att = (const float*)d_in[18];
    const float* c2bias = (const float*)d_in[19];
    const float* oW1 = (const float*)d_in[20]; const float* ob1 = (const float*)d_in[21];
    const float* oW2 = (const float*)d_in[22]; const float* ob2 = (const float*)d_in[23];
    const float* pW1 = (const float*)d_in[24]; const float* pb1 = (const float*)d_in[25];
    const float* pW2 = (const float*)d_in[26]; const float* pb2 = (const float*)d_in[27];
    float* out = (float*)d_out;

    // workspace layout (floats)
    float* fws = (float*)d_ws;
    size_t NH = (size_t)Nn * Hh;           // 3.2M
    float* h    = fws;
    float* xl   = fws + NH;
    float* xr   = fws + 2 * NH;
    int2*  epack = (int2*)(fws + 3 * NH);  // [Ee] packed (src, ea)
    float* g    = (float*)(epack + Ee);    // [Bb*128]
    int* iws = (int*)(g + (size_t)Bb * 128);
    int* counts = iws;                     // [Nn]
    int* off    = counts + Nn;             // [Nn+1]
    int* cursor = off + Nn + 1;            // [Nn]
    int* chk    = cursor + Nn;             // [128]
    int* gs     = chk + 128;               // [Bb]
    int* ge     = gs + Bb;                 // [Bb]

    const int* src = ei;
    const int* dst = ei + Ee;

    hipMemsetAsync(counts, 0, Nn * sizeof(int), stream);
    k_embed<<<(Nn * Hh + TPB - 1) / TPB, TPB, 0, stream>>>(x, embW, embB, h);
    k_hist<<<(Ee + TPB - 1) / TPB, TPB, 0, stream>>>(dst, counts);
    k_scan1<<<(Nn + CHUNK - 1) / CHUNK, CHUNK, 0, stream>>>(counts, off, chk);
    k_scan2<<<1, 64, 0, stream>>>(chk, (Nn + CHUNK - 1) / CHUNK);
    k_scan3<<<(Nn + 1 + TPB - 1) / TPB, TPB, 0, stream>>>(off, chk, cursor);
    k_scatter<<<(Ee + TPB - 1) / TPB, TPB, 0, stream>>>(src, dst, ea, cursor, epack);

    // conv1
    k_lin<<<Nn / 16, TPB, 0, stream>>>(h, c1Wl, c1bl, c1Wr, c1br, xl, xr);
    k_conv<<<(Nn * 64 + TPB - 1) / TPB, TPB, 0, stream>>>(xl, xr, epack, off, c1We, c1att, c1bias, h);

    // conv2
    k_lin<<<Nn / 16, TPB, 0, stream>>>(h, c2Wl, c2bl, c2Wr, c2br, xl, xr);
    k_conv<<<(Nn * 64 + TPB - 1) / TPB, TPB, 0, stream>>>(xl, xr, epack, off, c2We, c2att, c2bias, h);

    // fused RK4 (all 4 stages), 256 threads / 16 nodes
    k_ode4<<<Nn / 16, 256, 0, stream>>>(h, oW1, ob1, oW2, ob2);

    // pooling + head
    k_binit<<<1, Bb, 0, stream>>>(gs, ge);
    k_bounds<<<(Nn + TPB - 1) / TPB, TPB, 0, stream>>>(batch, gs, ge);
    k_pool<<<Bb, 256, 0, stream>>>(h, gs, ge, g);
    k_pred<<<(Bb * 64 + TPB - 1) / TPB, TPB, 0, stream>>>(g, pW1, pb1, pW2, pb2, out);
}